// Round 8
// baseline (345.361 us; speedup 1.0000x reference)
//
#include <hip/hip_runtime.h>

#define SEQ 2048
#define BATCH 4
#define DIM 1024
#define NHEAD 16
#define DHEAD 64

typedef __bf16 bf16;
typedef __bf16 bf16x8 __attribute__((ext_vector_type(8)));
typedef float f32x4 __attribute__((ext_vector_type(4)));
typedef unsigned int u32x4 __attribute__((ext_vector_type(4)));
typedef unsigned short u16;
typedef unsigned int u32;

__device__ __forceinline__ void gld16(const void* g, void* l) {
  __builtin_amdgcn_global_load_lds((__attribute__((address_space(1))) void*)(void*)g,
                                   (__attribute__((address_space(3))) void*)l, 16, 0, 0);
}

__device__ __forceinline__ u16 f2b(float f) {  // fp32 -> bf16 bits, RNE
  u32 u = __builtin_bit_cast(u32, f);
  u32 r = (u + 0x7FFFu + ((u >> 16) & 1u)) >> 16;
  return (u16)r;
}

// pack two f32 -> (bf16(f1)<<16)|bf16(f0), round-half-up (==RNE except exact ties)
__device__ __forceinline__ u32 pk2(float f0, float f1) {
  const u32 a = __builtin_bit_cast(u32, f1) + 0x8000u;
  const u32 b = __builtin_bit_cast(u32, f0) + 0x8000u;
  return __builtin_amdgcn_perm(a, b, 0x07060302u);
}

__device__ __forceinline__ void cvt16_store(const float4 v[4], u16* dst) {
  union { u16 h[16]; uint4 q[2]; } pk;
#pragma unroll
  for (int j = 0; j < 4; ++j) {
    pk.h[j * 4 + 0] = f2b(v[j].x);
    pk.h[j * 4 + 1] = f2b(v[j].y);
    pk.h[j * 4 + 2] = f2b(v[j].z);
    pk.h[j * 4 + 3] = f2b(v[j].w);
  }
  ((uint4*)dst)[0] = pk.q[0];
  ((uint4*)dst)[1] = pk.q[1];
}

// ---------------- K0: one-shot f32 -> bf16 conversion ----------------
__global__ __launch_bounds__(256) void k_cvt(
    const float* __restrict__ inp, const float* __restrict__ wqkv,
    const float* __restrict__ wproj, u16* __restrict__ xb,
    u16* __restrict__ wqkvb, u16* __restrict__ wprojb) {
  const int idx = blockIdx.x * 256 + threadIdx.x;
  const float4* src;
  u16* dst;
  int off;
  if (idx < 2097152)      { src = (const float4*)inp;   dst = xb;     off = idx; }
  else if (idx < 2883584) { src = (const float4*)wqkv;  dst = wqkvb;  off = idx - 2097152; }
  else                    { src = (const float4*)wproj; dst = wprojb; off = idx - 2883584; }
  const float4 v = src[off];
  union { u16 h[4]; uint2 q; } pk;
  pk.h[0] = f2b(v.x); pk.h[1] = f2b(v.y); pk.h[2] = f2b(v.z); pk.h[3] = f2b(v.w);
  *(uint2*)(dst + (size_t)off * 4) = pk.q;
}

// ---------------- K1a: QKV projection, all-bf16, async staging ----------------
__global__ __launch_bounds__(256, 2) void k_qkv_a(
    const u16* __restrict__ xb, const u16* __restrict__ wb,
    const float* __restrict__ bqkv, u16* __restrict__ q,
    u16* __restrict__ kk, u16* __restrict__ v) {
  __shared__ __align__(16) u16 Asm[128 * 32];
  __shared__ __align__(16) u16 Bsm[128 * 32];
  const int bn = blockIdx.x;   // 0..23
  const int bm = blockIdx.y;   // 0..63
  const int tid = threadIdx.x;
  const int wave = tid >> 6, lane = tid & 63;
  const int col = lane & 15, quad = lane >> 4;
  const int b = bm >> 4;
  const int s0 = (bm & 15) * 128;
  const int c0 = wave * 2;
  const int srow0 = c0 * 16 + (lane >> 2);
  const int kc = (lane & 3) * 8;
  const u16* gA0 = xb + (size_t)((s0 + srow0) * 4 + b) * 1024 + kc;
  const u16* gA1 = xb + (size_t)((s0 + srow0 + 16) * 4 + b) * 1024 + kc;
  const u16* gB0 = wb + (size_t)(bn * 128 + srow0) * 1024 + kc;
  const u16* gB1 = wb + (size_t)(bn * 128 + srow0 + 16) * 1024 + kc;
  u16* lA0 = Asm + c0 * 512;
  u16* lA1 = Asm + c0 * 512 + 512;
  u16* lB0 = Bsm + c0 * 512;
  u16* lB1 = Bsm + c0 * 512 + 512;
  const int wm = (wave >> 1) * 64, wn = (wave & 1) * 64;

  f32x4 acc[4][4];
#pragma unroll
  for (int i = 0; i < 4; ++i)
#pragma unroll
    for (int j = 0; j < 4; ++j) acc[i][j] = f32x4{0.f, 0.f, 0.f, 0.f};

  for (int k0 = 0; k0 < 1024; k0 += 32) {
    __syncthreads();
    gld16(gA0 + k0, lA0);
    gld16(gA1 + k0, lA1);
    gld16(gB0 + k0, lB0);
    gld16(gB1 + k0, lB1);
    __builtin_amdgcn_s_waitcnt(0);
    __syncthreads();
    bf16x8 af[4], bfr[4];
#pragma unroll
    for (int i = 0; i < 4; ++i)
      af[i] = *(const bf16x8*)(Asm + (wm + i * 16 + col) * 32 + quad * 8);
#pragma unroll
    for (int j = 0; j < 4; ++j)
      bfr[j] = *(const bf16x8*)(Bsm + (wn + j * 16 + col) * 32 + quad * 8);
#pragma unroll
    for (int i = 0; i < 4; ++i)
#pragma unroll
      for (int j = 0; j < 4; ++j)
        acc[i][j] = __builtin_amdgcn_mfma_f32_16x16x32_bf16(af[i], bfr[j], acc[i][j], 0, 0, 0);
  }

  const float QS = 0.125f * 1.44269504088896f;  // SCALE * log2(e)
#pragma unroll
  for (int j = 0; j < 4; ++j) {
    const int n = bn * 128 + wn + j * 16 + col;
    const float bias = bqkv[n];
    const int region = n >> 10;  // 0=q 1=k 2=v
    const int hh = (n >> 6) & 15;
    const int dh = n & 63;
    if (region == 2) {  // V transposed: [B,H,DH,S]
      const size_t baseT = ((size_t)(b * 16 + hh) * 64 + dh) * 2048;
#pragma unroll
      for (int i = 0; i < 4; ++i) {
        const int srow = s0 + wm + i * 16 + quad * 4;
#pragma unroll
        for (int r = 0; r < 4; ++r)
          v[baseT + srow + r] = f2b(acc[i][j][r] + bias);
      }
    } else {
      u16* outp = (region == 0) ? q : kk;
      const float mult = (region == 0) ? QS : 1.0f;
      const size_t base = ((size_t)(b * 16 + hh) * 2048) * 64 + dh;
#pragma unroll
      for (int i = 0; i < 4; ++i) {
        const int srow = s0 + wm + i * 16 + quad * 4;
#pragma unroll
        for (int r = 0; r < 4; ++r)
          outp[base + (size_t)(srow + r) * 64] = f2b((acc[i][j][r] + bias) * mult);
      }
    }
  }
}

// ---------------- K1b: QKV projection, f32-inline-convert (fallback) ----------------
__global__ __launch_bounds__(256, 2) void k_qkv_f32(
    const float* __restrict__ inp, const float* __restrict__ Wqkv,
    const float* __restrict__ bqkv, u16* __restrict__ q,
    u16* __restrict__ kk, u16* __restrict__ v, int b_fixed) {
  __shared__ __align__(16) u16 Asm[128 * 32];
  __shared__ __align__(16) u16 Bsm[128 * 32];
  const int bn = blockIdx.x;
  const int bm = blockIdx.y;
  const int tid = threadIdx.x;
  const int wave = tid >> 6, lane = tid & 63;
  const int col = lane & 15, quad = lane >> 4;
  int b, s0, hb;
  if (b_fixed < 0) { b = bm >> 4; s0 = (bm & 15) * 128; hb = b * 16; }
  else             { b = b_fixed; s0 = bm * 128;        hb = 0; }

  const int arow = tid >> 1;
  const int kseg = (tid & 1) * 16;
  const float* gA = inp + (size_t)((s0 + arow) * 4 + b) * 1024 + kseg;
  const float* gB = Wqkv + (size_t)(bn * 128 + arow) * 1024 + kseg;
  u16* lA = Asm + arow * 32 + kseg;
  u16* lB = Bsm + arow * 32 + kseg;
  const int wm = (wave >> 1) * 64, wn = (wave & 1) * 64;

  f32x4 acc[4][4];
#pragma unroll
  for (int i = 0; i < 4; ++i)
#pragma unroll
    for (int j = 0; j < 4; ++j) acc[i][j] = f32x4{0.f, 0.f, 0.f, 0.f};

  for (int k0 = 0; k0 < 1024; k0 += 32) {
    float4 av[4], bv[4];
#pragma unroll
    for (int u = 0; u < 4; ++u) av[u] = *(const float4*)(gA + k0 + u * 4);
#pragma unroll
    for (int u = 0; u < 4; ++u) bv[u] = *(const float4*)(gB + k0 + u * 4);
    __syncthreads();
    cvt16_store(av, lA);
    cvt16_store(bv, lB);
    __syncthreads();
    bf16x8 af[4], bfr[4];
#pragma unroll
    for (int i = 0; i < 4; ++i)
      af[i] = *(const bf16x8*)(Asm + (wm + i * 16 + col) * 32 + quad * 8);
#pragma unroll
    for (int j = 0; j < 4; ++j)
      bfr[j] = *(const bf16x8*)(Bsm + (wn + j * 16 + col) * 32 + quad * 8);
#pragma unroll
    for (int i = 0; i < 4; ++i)
#pragma unroll
      for (int j = 0; j < 4; ++j)
        acc[i][j] = __builtin_amdgcn_mfma_f32_16x16x32_bf16(af[i], bfr[j], acc[i][j], 0, 0, 0);
  }

  const float QS = 0.125f * 1.44269504088896f;
#pragma unroll
  for (int j = 0; j < 4; ++j) {
    const int n = bn * 128 + wn + j * 16 + col;
    const float bias = bqkv[n];
    const int region = n >> 10;
    const int hh = (n >> 6) & 15;
    const int dh = n & 63;
    if (region == 2) {
      const size_t baseT = ((size_t)(hb + hh) * 64 + dh) * 2048;
#pragma unroll
      for (int i = 0; i < 4; ++i) {
        const int srow = s0 + wm + i * 16 + quad * 4;
#pragma unroll
        for (int r = 0; r < 4; ++r)
          v[baseT + srow + r] = f2b(acc[i][j][r] + bias);
      }
    } else {
      u16* outp = (region == 0) ? q : kk;
      const float mult = (region == 0) ? QS : 1.0f;
      const size_t base = ((size_t)(hb + hh) * 2048) * 64 + dh;
#pragma unroll
      for (int i = 0; i < 4; ++i) {
        const int srow = s0 + wm + i * 16 + quad * 4;
#pragma unroll
        for (int r = 0; r < 4; ++r)
          outp[base + (size_t)(srow + r) * 64] = f2b((acc[i][j][r] + bias) * mult);
      }
    }
  }
}

// ---------------- K2: flash attention (merged 64-key softmax) ----------------
// One online-softmax update per 64-key tile (was 2x32). Mask bias folded into
// the QK MFMA C-initializer (zero-cost masking). P relay extended to 16x64
// per qt, same conflict-free bank pattern: write u32 @ mt*128+quad*32+col*2,
// read @ c*256+quad*64+col*2 (+1,+32,+33) -> banks {2col,2col+1} per 16-lane
// phase, verified 0 conflicts in R7 for the 32-key variant.
__global__ __launch_bounds__(256, 4) void k_attn(
    const u16* __restrict__ q, const u16* __restrict__ k,
    const u16* __restrict__ v, const int* __restrict__ mask,
    u16* __restrict__ attn, int b_fixed) {
  __shared__ __align__(16) float Msmf[2048];  // 8KB mask bias row
  __shared__ __align__(16) u16 Ksm[64 * 64];  // 8KB
  __shared__ __align__(16) u16 Vsm[64 * 64];  // 8KB
  __shared__ __align__(16) u32 PsmU[4096];    // 16KB P relay (wave-private)
  const int bid = blockIdx.x;
  const int tid = threadIdx.x, wave = tid >> 6, lane = tid & 63;
  const int col = lane & 15, quad = lane >> 4;
  int qblk, h, b, hb;
  if (b_fixed < 0) { qblk = bid & 15; h = (bid >> 4) & 15; b = bid >> 8; hb = b * 16 + h; }
  else             { qblk = bid & 15; h = bid >> 4;        b = b_fixed;  hb = h; }
  const size_t bh = (size_t)hb * 2048 * 64;

  {  // stage mask row b (2048 int32)
    const int c = wave * 2;
    gld16(mask + b * 2048 + c * 256 + lane * 4, (char*)Msmf + c * 1024);
    gld16(mask + b * 2048 + (c + 1) * 256 + lane * 4, (char*)Msmf + (c + 1) * 1024);
  }
  __builtin_amdgcn_s_waitcnt(0);
  __syncthreads();
  for (int i = tid; i < 2048; i += 256) {
    const int mi = ((const int*)Msmf)[i];
    Msmf[i] = mi ? -1e30f : 0.f;
  }

  bf16x8 qf[2][2];
#pragma unroll
  for (int qt = 0; qt < 2; ++qt)
#pragma unroll
    for (int c = 0; c < 2; ++c)
      qf[qt][c] = *(const bf16x8*)(q + bh +
                   (size_t)(qblk * 128 + wave * 32 + qt * 16 + col) * 64 + c * 32 + quad * 8);

  f32x4 o[2][4];
#pragma unroll
  for (int qt = 0; qt < 2; ++qt)
#pragma unroll
    for (int n = 0; n < 4; ++n) o[qt][n] = f32x4{0.f, 0.f, 0.f, 0.f};
  float mrun[2] = {-1e30f, -1e30f}, lrun[2] = {0.f, 0.f};

  const int r8 = lane >> 3, chn = lane & 7;
  const int g = chn ^ r8;
  const int swz = col & 7;
  __syncthreads();

  for (int kt = 0; kt < 32; ++kt) {
    __syncthreads();
#pragma unroll
    for (int s = 0; s < 2; ++s) {
      const int row = (wave * 2 + s) * 8 + r8;
      gld16(k + bh + (size_t)(kt * 64 + row) * 64 + g * 8,
            (char*)Ksm + (wave * 2 + s) * 1024);
      gld16(v + bh + (size_t)row * 2048 + kt * 64 + g * 8,
            (char*)Vsm + (wave * 2 + s) * 1024);
    }
    __builtin_amdgcn_s_waitcnt(0);
    __syncthreads();

    bf16x8 ka[4][2];
#pragma unroll
    for (int mt = 0; mt < 4; ++mt)
#pragma unroll
      for (int c2 = 0; c2 < 2; ++c2)
        ka[mt][c2] = *(const bf16x8*)((const char*)Ksm +
            (mt * 16 + col) * 128 + ((c2 * 4 + quad) ^ swz) * 16);

    float alpha[2];
#pragma unroll
    for (int qt = 0; qt < 2; ++qt) {
      f32x4 sc[4];
#pragma unroll
      for (int mt = 0; mt < 4; ++mt) {
        const float4 mbv = *(const float4*)(Msmf + kt * 64 + mt * 16 + quad * 4);
        f32x4 z = {mbv.x, mbv.y, mbv.z, mbv.w};  // mask bias as C-init
        z = __builtin_amdgcn_mfma_f32_16x16x32_bf16(ka[mt][0], qf[qt][0], z, 0, 0, 0);
        sc[mt] = __builtin_amdgcn_mfma_f32_16x16x32_bf16(ka[mt][1], qf[qt][1], z, 0, 0, 0);
      }
      float tm = fmaxf(fmaxf(sc[0][0], sc[0][1]), fmaxf(sc[0][2], sc[0][3]));
#pragma unroll
      for (int mt = 1; mt < 4; ++mt)
#pragma unroll
        for (int r = 0; r < 4; ++r) tm = fmaxf(tm, sc[mt][r]);
      tm = fmaxf(tm, __shfl_xor(tm, 16, 64));
      tm = fmaxf(tm, __shfl_xor(tm, 32, 64));
      const float mnew = fmaxf(mrun[qt], tm);
      alpha[qt] = __builtin_amdgcn_exp2f(mrun[qt] - mnew);
      mrun[qt] = mnew;
      float sum = 0.f;
#pragma unroll
      for (int mt = 0; mt < 4; ++mt)
#pragma unroll
        for (int r = 0; r < 4; ++r) {
          sc[mt][r] = __builtin_amdgcn_exp2f(sc[mt][r] - mnew);
          sum += sc[mt][r];
        }
      sum += __shfl_xor(sum, 16, 64);
      sum += __shfl_xor(sum, 32, 64);
      lrun[qt] = lrun[qt] * alpha[qt] + sum;
      u32* pw = PsmU + (wave * 2 + qt) * 512 + quad * 32 + col * 2;
#pragma unroll
      for (int mt = 0; mt < 4; ++mt) {
        uint2 w;
        w.x = pk2(sc[mt][0], sc[mt][1]);
        w.y = pk2(sc[mt][2], sc[mt][3]);
        *(uint2*)(pw + mt * 128) = w;
      }
    }

    asm volatile("s_waitcnt lgkmcnt(0)" ::: "memory");

    bf16x8 pa[2][2];
#pragma unroll
    for (int qt = 0; qt < 2; ++qt)
#pragma unroll
      for (int c = 0; c < 2; ++c) {
        const u32* pr = PsmU + (wave * 2 + qt) * 512 + c * 256 + quad * 64 + col * 2;
        const uint2 a0 = *(const uint2*)pr;
        const uint2 a1 = *(const uint2*)(pr + 32);
        u32x4 w = {a0.x, a0.y, a1.x, a1.y};
        pa[qt][c] = __builtin_bit_cast(bf16x8, w);
      }

    float ar[2][4];
#pragma unroll
    for (int qt = 0; qt < 2; ++qt)
#pragma unroll
      for (int r = 0; r < 4; ++r) ar[qt][r] = __shfl(alpha[qt], quad * 4 + r, 64);

#pragma unroll
    for (int n = 0; n < 4; ++n) {
      const bf16x8 vb0 = *(const bf16x8*)((const char*)Vsm +
          (n * 16 + col) * 128 + (quad ^ swz) * 16);
      const bf16x8 vb1 = *(const bf16x8*)((const char*)Vsm +
          (n * 16 + col) * 128 + ((4 + quad) ^ swz) * 16);
#pragma unroll
      for (int qt = 0; qt < 2; ++qt) {
        f32x4 t = o[qt][n];
#pragma unroll
        for (int r = 0; r < 4; ++r) t[r] *= ar[qt][r];
        t = __builtin_amdgcn_mfma_f32_16x16x32_bf16(pa[qt][0], vb0, t, 0, 0, 0);
        o[qt][n] = __builtin_amdgcn_mfma_f32_16x16x32_bf16(pa[qt][1], vb1, t, 0, 0, 0);
      }
    }
  }

  const int arow0 = (b_fixed < 0) ? b * 2048 : 0;
#pragma unroll
  for (int qt = 0; qt < 2; ++qt) {
    float inv[4];
#pragma unroll
    for (int r = 0; r < 4; ++r) {
      const float lr = __shfl(lrun[qt], quad * 4 + r, 64);
      inv[r] = 1.0f / lr;
    }
#pragma unroll
    for (int n = 0; n < 4; ++n)
#pragma unroll
      for (int r = 0; r < 4; ++r) {
        const int srow = qblk * 128 + wave * 32 + qt * 16 + quad * 4 + r;
        const size_t idx = ((size_t)(arow0 + srow)) * 1024 + h * 64 + n * 16 + col;
        attn[idx] = f2b(o[qt][n][r] * inv[r]);
      }
  }
}

// ---------------- K3a: output projection, all-bf16 staging ----------------
__global__ __launch_bounds__(256, 2) void k_proj_a(
    const u16* __restrict__ attn, const u16* __restrict__ wb,
    const float* __restrict__ bproj, float* __restrict__ out) {
  __shared__ __align__(16) u16 Asm[128 * 32];
  __shared__ __align__(16) u16 Bsm[128 * 32];
  const int bn = blockIdx.x;  // 0..7
  const int bm = blockIdx.y;  // 0..63
  const int tid = threadIdx.x;
  const int wave = tid >> 6, lane = tid & 63;
  const int col = lane & 15, quad = lane >> 4;
  const int b = bm >> 4;
  const int s0 = (bm & 15) * 128;
  const int c0 = wave * 2;
  const int srow0 = c0 * 16 + (lane >> 2);
  const int kc = (lane & 3) * 8;
  const u16* gA0 = attn + (size_t)(bm * 128 + srow0) * 1024 + kc;
  const u16* gA1 = attn + (size_t)(bm * 128 + srow0 + 16) * 1024 + kc;
  const u16* gB0 = wb + (size_t)(bn * 128 + srow0) * 1024 + kc;
  const u16* gB1 = wb + (size_t)(bn * 128 + srow0 + 16) * 1024 + kc;
  u16* lA0 = Asm + c0 * 512;
  u16* lA1 = Asm + c0 * 512 + 512;
  u16* lB0 = Bsm + c0 * 512;
  u16* lB1 = Bsm + c0 * 512 + 512;
  const int wm = (wave >> 1) * 64, wn = (wave & 1) * 64;

  f32x4 acc[4][4];
#pragma unroll
  for (int i = 0; i < 4; ++i)
#pragma unroll
    for (int j = 0; j < 4; ++j) acc[i][j] = f32x4{0.f, 0.f, 0.f, 0.f};

  for (int k0 = 0; k0 < 1024; k0 += 32) {
    __syncthreads();
    gld16(gA0 + k0, lA0);
    gld16(gA1 + k0, lA1);
    gld16(gB0 + k0, lB0);
    gld16(gB1 + k0, lB1);
    __builtin_amdgcn_s_waitcnt(0);
    __syncthreads();
    bf16x8 af[4], bfr[4];
#pragma unroll
    for (int i = 0; i < 4; ++i)
      af[i] = *(const bf16x8*)(Asm + (wm + i * 16 + col) * 32 + quad * 8);
#pragma unroll
    for (int j = 0; j < 4; ++j)
      bfr[j] = *(const bf16x8*)(Bsm + (wn + j * 16 + col) * 32 + quad * 8);
#pragma unroll
    for (int i = 0; i < 4; ++i)
#pragma unroll
      for (int j = 0; j < 4; ++j)
        acc[i][j] = __builtin_amdgcn_mfma_f32_16x16x32_bf16(af[i], bfr[j], acc[i][j], 0, 0, 0);
  }

#pragma unroll
  for (int j = 0; j < 4; ++j) {
    const int n = bn * 128 + wn + j * 16 + col;
    const float bias = bproj[n];
#pragma unroll
    for (int i = 0; i < 4; ++i) {
      const int srow = s0 + wm + i * 16 + quad * 4;
#pragma unroll
      for (int r = 0; r < 4; ++r)
        out[(size_t)((srow + r) * 4 + b) * 1024 + n] = acc[i][j][r] + bias;
    }
  }
}

// ---------------- K3b: output projection, inline-convert B (fallback) ----------------
__global__ __launch_bounds__(256, 2) void k_proj_f32(
    const u16* __restrict__ attn, const float* __restrict__ Wproj,
    const float* __restrict__ bproj, float* __restrict__ out, int b_fixed) {
  __shared__ __align__(16) u16 Asm[128 * 32];
  __shared__ __align__(16) u16 Bsm[128 * 32];
  const int bn = blockIdx.x;
  const int bm = blockIdx.y;
  const int tid = threadIdx.x;
  const int wave = tid >> 6, lane = tid & 63;
  const int col = lane & 15, quad = lane >> 4;
  int b, s0;
  if (b_fixed < 0) { b = bm >> 4; s0 = (bm & 15) * 128; }
  else             { b = b_fixed; s0 = bm * 128; }

  const int c0 = wave * 2;
  const int srow0 = c0 * 16 + (lane >> 2);
  const int kc = (lane & 3) * 8;
  const u16* gA0 = attn + (size_t)(bm * 128 + srow0) * 1024 + kc;
  const u16* gA1 = attn + (size_t)(bm * 128 + srow0 + 16) * 1024 + kc;
  u16* lA0 = Asm + c0 * 512;
  u16* lA1 = Asm + c0 * 512 + 512;
  const int brow = tid >> 1;
  const int kseg = (tid & 1) * 16;
  const float* gB = Wproj + (size_t)(bn * 128 + brow) * 1024 + kseg;
  u16* lB = Bsm + brow * 32 + kseg;
  const int wm = (wave >> 1) * 64, wn = (wave & 1) * 64;

  f32x4 acc[4][4];
#pragma unroll
  for (int i = 0; i < 4; ++i)
#pragma unroll
    for (int j = 0; j < 4; ++j) acc[i][j] = f32x4{0.f, 0.f, 0.f, 0.f};

  for (int k0 = 0; k0 < 1024; k0 += 32) {
    float4 bv[4];
#pragma unroll
    for (int u = 0; u < 4; ++u) bv[u] = *(const float4*)(gB + k0 + u * 4);
    __syncthreads();
    gld16(gA0 + k0, lA0);
    gld16(gA1 + k0, lA1);
    cvt16_store(bv, lB);
    __builtin_amdgcn_s_waitcnt(0);
    __syncthreads();
    bf16x8 af[4], bfr[4];
#pragma unroll
    for (int i = 0; i < 4; ++i)
      af[i] = *(const bf16x8*)(Asm + (wm + i * 16 + col) * 32 + quad * 8);
#pragma unroll
    for (int j = 0; j < 4; ++j)
      bfr[j] = *(const bf16x8*)(Bsm + (wn + j * 16 + col) * 32 + quad * 8);
#pragma unroll
    for (int i = 0; i < 4; ++i)
#pragma unroll
      for (int j = 0; j < 4; ++j)
        acc[i][j] = __builtin_amdgcn_mfma_f32_16x16x32_bf16(af[i], bfr[j], acc[i][j], 0, 0, 0);
  }

#pragma unroll
  for (int j = 0; j < 4; ++j) {
    const int n = bn * 128 + wn + j * 16 + col;
    const float bias = bproj[n];
#pragma unroll
    for (int i = 0; i < 4; ++i) {
      const int srow = s0 + wm + i * 16 + quad * 4;
#pragma unroll
      for (int r = 0; r < 4; ++r)
        out[(size_t)((srow + r) * 4 + b) * 1024 + n] = acc[i][j][r] + bias;
    }
  }
}

extern "C" void kernel_launch(void* const* d_in, const int* in_sizes, int n_in,
                              void* d_out, int out_size, void* d_ws, size_t ws_size,
                              hipStream_t stream) {
  const float* inp = (const float*)d_in[0];
  const int* mask = (const int*)d_in[1];
  const float* Wqkv = (const float*)d_in[2];
  const float* bqkv = (const float*)d_in[3];
  const float* Wproj = (const float*)d_in[4];
  const float* bproj = (const float*)d_in[5];
  float* out = (float*)d_out;

  const size_t FULLSZ = (size_t)BATCH * NHEAD * SEQ * DHEAD;  // 8388608 elems
  const size_t WQKV_E = (size_t)3 * DIM * DIM;                // 3145728
  const size_t WPROJ_E = (size_t)DIM * DIM;                   // 1048576
  const size_t pathA_bytes = (4 * FULLSZ + WQKV_E + WPROJ_E) * sizeof(u16);  // 75.5 MB

  if (ws_size >= pathA_bytes) {
    // Path A: convert-once + all-async-bf16 GEMMs.
    u16* q = (u16*)d_ws;
    u16* kk = q + FULLSZ;
    u16* v = kk + FULLSZ;
    u16* xb = v + FULLSZ;      // converted inp; later overwritten as attn buffer
    u16* attn = xb;            // alias — k_attn writes after k_qkv_a finished reading
    u16* wqkvb = xb + FULLSZ;
    u16* wprojb = wqkvb + WQKV_E;
    k_cvt<<<dim3(12288), 256, 0, stream>>>(inp, Wqkv, Wproj, xb, wqkvb, wprojb);
    k_qkv_a<<<dim3(24, 64), 256, 0, stream>>>(xb, wqkvb, bqkv, q, kk, v);
    k_attn<<<dim3(1024), 256, 0, stream>>>(q, kk, v, mask, attn, -1);
    k_proj_a<<<dim3(8, 64), 256, 0, stream>>>(attn, wprojb, bproj, out);
  } else if (ws_size >= 4 * FULLSZ * sizeof(u16)) {
    // Path B: proven R5 pipeline (inline f32 convert).
    u16* q = (u16*)d_ws;
    u16* kk = q + FULLSZ;
    u16* v = kk + FULLSZ;
    u16* attn = v + FULLSZ;
    k_qkv_f32<<<dim3(24, 64), 256, 0, stream>>>(inp, Wqkv, bqkv, q, kk, v, -1);
    k_attn<<<dim3(1024), 256, 0, stream>>>(q, kk, v, mask, attn, -1);
    k_proj_f32<<<dim3(8, 64), 256, 0, stream>>>(attn, Wproj, bproj, out, -1);
  } else {
    // Path C: per-batch pipeline, 16 MiB workspace.
    const size_t BSZ = (size_t)NHEAD * SEQ * DHEAD;
    u16* q = (u16*)d_ws;
    u16* kk = q + BSZ;
    u16* v = kk + BSZ;
    u16* attn = v + BSZ;
    for (int b = 0; b < BATCH; ++b) {
      k_qkv_f32<<<dim3(24, 16), 256, 0, stream>>>(inp, Wqkv, bqkv, q, kk, v, b);
      k_attn<<<dim3(256), 256, 0, stream>>>(q, kk, v, mask, attn, b);
      k_proj_f32<<<dim3(8, 16), 256, 0, stream>>>(attn, Wproj, bproj, out, b);
    }
  }
}

// Round 9
// 315.628 us; speedup vs baseline: 1.0942x; 1.0942x over previous
//
#include <hip/hip_runtime.h>

#define SEQ 2048
#define BATCH 4
#define DIM 1024
#define NHEAD 16
#define DHEAD 64

typedef __bf16 bf16;
typedef __bf16 bf16x8 __attribute__((ext_vector_type(8)));
typedef float f32x4 __attribute__((ext_vector_type(4)));
typedef unsigned int u32x4 __attribute__((ext_vector_type(4)));
typedef unsigned short u16;
typedef unsigned int u32;

__device__ __forceinline__ void gld16(const void* g, void* l) {
  __builtin_amdgcn_global_load_lds((__attribute__((address_space(1))) void*)(void*)g,
                                   (__attribute__((address_space(3))) void*)l, 16, 0, 0);
}

__device__ __forceinline__ u16 f2b(float f) {  // fp32 -> bf16 bits, RNE
  u32 u = __builtin_bit_cast(u32, f);
  u32 r = (u + 0x7FFFu + ((u >> 16) & 1u)) >> 16;
  return (u16)r;
}

// pack two f32 -> (bf16(f1)<<16)|bf16(f0), round-half-up (==RNE except exact ties)
__device__ __forceinline__ u32 pk2(float f0, float f1) {
  const u32 a = __builtin_bit_cast(u32, f1) + 0x8000u;
  const u32 b = __builtin_bit_cast(u32, f0) + 0x8000u;
  return __builtin_amdgcn_perm(a, b, 0x07060302u);
}

__device__ __forceinline__ void cvt16_store(const float4 v[4], u16* dst) {
  union { u16 h[16]; uint4 q[2]; } pk;
#pragma unroll
  for (int j = 0; j < 4; ++j) {
    pk.h[j * 4 + 0] = f2b(v[j].x);
    pk.h[j * 4 + 1] = f2b(v[j].y);
    pk.h[j * 4 + 2] = f2b(v[j].z);
    pk.h[j * 4 + 3] = f2b(v[j].w);
  }
  ((uint4*)dst)[0] = pk.q[0];
  ((uint4*)dst)[1] = pk.q[1];
}

// ---------------- K0: one-shot f32 -> bf16 conversion ----------------
__global__ __launch_bounds__(256) void k_cvt(
    const float* __restrict__ inp, const float* __restrict__ wqkv,
    const float* __restrict__ wproj, u16* __restrict__ xb,
    u16* __restrict__ wqkvb, u16* __restrict__ wprojb) {
  const int idx = blockIdx.x * 256 + threadIdx.x;
  const float4* src;
  u16* dst;
  int off;
  if (idx < 2097152)      { src = (const float4*)inp;   dst = xb;     off = idx; }
  else if (idx < 2883584) { src = (const float4*)wqkv;  dst = wqkvb;  off = idx - 2097152; }
  else                    { src = (const float4*)wproj; dst = wprojb; off = idx - 2883584; }
  const float4 v = src[off];
  union { u16 h[4]; uint2 q; } pk;
  pk.h[0] = f2b(v.x); pk.h[1] = f2b(v.y); pk.h[2] = f2b(v.z); pk.h[3] = f2b(v.w);
  *(uint2*)(dst + (size_t)off * 4) = pk.q;
}

// ---------------- K1a: QKV projection, all-bf16, async staging ----------------
__global__ __launch_bounds__(256, 2) void k_qkv_a(
    const u16* __restrict__ xb, const u16* __restrict__ wb,
    const float* __restrict__ bqkv, u16* __restrict__ q,
    u16* __restrict__ kk, u16* __restrict__ v) {
  __shared__ __align__(16) u16 Asm[128 * 32];
  __shared__ __align__(16) u16 Bsm[128 * 32];
  const int bn = blockIdx.x;   // 0..23
  const int bm = blockIdx.y;   // 0..63
  const int tid = threadIdx.x;
  const int wave = tid >> 6, lane = tid & 63;
  const int col = lane & 15, quad = lane >> 4;
  const int b = bm >> 4;
  const int s0 = (bm & 15) * 128;
  const int c0 = wave * 2;
  const int srow0 = c0 * 16 + (lane >> 2);
  const int kc = (lane & 3) * 8;
  const u16* gA0 = xb + (size_t)((s0 + srow0) * 4 + b) * 1024 + kc;
  const u16* gA1 = xb + (size_t)((s0 + srow0 + 16) * 4 + b) * 1024 + kc;
  const u16* gB0 = wb + (size_t)(bn * 128 + srow0) * 1024 + kc;
  const u16* gB1 = wb + (size_t)(bn * 128 + srow0 + 16) * 1024 + kc;
  u16* lA0 = Asm + c0 * 512;
  u16* lA1 = Asm + c0 * 512 + 512;
  u16* lB0 = Bsm + c0 * 512;
  u16* lB1 = Bsm + c0 * 512 + 512;
  const int wm = (wave >> 1) * 64, wn = (wave & 1) * 64;

  f32x4 acc[4][4];
#pragma unroll
  for (int i = 0; i < 4; ++i)
#pragma unroll
    for (int j = 0; j < 4; ++j) acc[i][j] = f32x4{0.f, 0.f, 0.f, 0.f};

  for (int k0 = 0; k0 < 1024; k0 += 32) {
    __syncthreads();
    gld16(gA0 + k0, lA0);
    gld16(gA1 + k0, lA1);
    gld16(gB0 + k0, lB0);
    gld16(gB1 + k0, lB1);
    __builtin_amdgcn_s_waitcnt(0);
    __syncthreads();
    bf16x8 af[4], bfr[4];
#pragma unroll
    for (int i = 0; i < 4; ++i)
      af[i] = *(const bf16x8*)(Asm + (wm + i * 16 + col) * 32 + quad * 8);
#pragma unroll
    for (int j = 0; j < 4; ++j)
      bfr[j] = *(const bf16x8*)(Bsm + (wn + j * 16 + col) * 32 + quad * 8);
#pragma unroll
    for (int i = 0; i < 4; ++i)
#pragma unroll
      for (int j = 0; j < 4; ++j)
        acc[i][j] = __builtin_amdgcn_mfma_f32_16x16x32_bf16(af[i], bfr[j], acc[i][j], 0, 0, 0);
  }

  const float QS = 0.125f * 1.44269504088896f;  // SCALE * log2(e)
#pragma unroll
  for (int j = 0; j < 4; ++j) {
    const int n = bn * 128 + wn + j * 16 + col;
    const float bias = bqkv[n];
    const int region = n >> 10;  // 0=q 1=k 2=v
    const int hh = (n >> 6) & 15;
    const int dh = n & 63;
    if (region == 2) {  // V transposed: [B,H,DH,S]
      const size_t baseT = ((size_t)(b * 16 + hh) * 64 + dh) * 2048;
#pragma unroll
      for (int i = 0; i < 4; ++i) {
        const int srow = s0 + wm + i * 16 + quad * 4;
#pragma unroll
        for (int r = 0; r < 4; ++r)
          v[baseT + srow + r] = f2b(acc[i][j][r] + bias);
      }
    } else {
      u16* outp = (region == 0) ? q : kk;
      const float mult = (region == 0) ? QS : 1.0f;
      const size_t base = ((size_t)(b * 16 + hh) * 2048) * 64 + dh;
#pragma unroll
      for (int i = 0; i < 4; ++i) {
        const int srow = s0 + wm + i * 16 + quad * 4;
#pragma unroll
        for (int r = 0; r < 4; ++r)
          outp[base + (size_t)(srow + r) * 64] = f2b((acc[i][j][r] + bias) * mult);
      }
    }
  }
}

// ---------------- K1b: QKV projection, f32-inline-convert (fallback) ----------------
__global__ __launch_bounds__(256, 2) void k_qkv_f32(
    const float* __restrict__ inp, const float* __restrict__ Wqkv,
    const float* __restrict__ bqkv, u16* __restrict__ q,
    u16* __restrict__ kk, u16* __restrict__ v, int b_fixed) {
  __shared__ __align__(16) u16 Asm[128 * 32];
  __shared__ __align__(16) u16 Bsm[128 * 32];
  const int bn = blockIdx.x;
  const int bm = blockIdx.y;
  const int tid = threadIdx.x;
  const int wave = tid >> 6, lane = tid & 63;
  const int col = lane & 15, quad = lane >> 4;
  int b, s0, hb;
  if (b_fixed < 0) { b = bm >> 4; s0 = (bm & 15) * 128; hb = b * 16; }
  else             { b = b_fixed; s0 = bm * 128;        hb = 0; }

  const int arow = tid >> 1;
  const int kseg = (tid & 1) * 16;
  const float* gA = inp + (size_t)((s0 + arow) * 4 + b) * 1024 + kseg;
  const float* gB = Wqkv + (size_t)(bn * 128 + arow) * 1024 + kseg;
  u16* lA = Asm + arow * 32 + kseg;
  u16* lB = Bsm + arow * 32 + kseg;
  const int wm = (wave >> 1) * 64, wn = (wave & 1) * 64;

  f32x4 acc[4][4];
#pragma unroll
  for (int i = 0; i < 4; ++i)
#pragma unroll
    for (int j = 0; j < 4; ++j) acc[i][j] = f32x4{0.f, 0.f, 0.f, 0.f};

  for (int k0 = 0; k0 < 1024; k0 += 32) {
    float4 av[4], bv[4];
#pragma unroll
    for (int u = 0; u < 4; ++u) av[u] = *(const float4*)(gA + k0 + u * 4);
#pragma unroll
    for (int u = 0; u < 4; ++u) bv[u] = *(const float4*)(gB + k0 + u * 4);
    __syncthreads();
    cvt16_store(av, lA);
    cvt16_store(bv, lB);
    __syncthreads();
    bf16x8 af[4], bfr[4];
#pragma unroll
    for (int i = 0; i < 4; ++i)
      af[i] = *(const bf16x8*)(Asm + (wm + i * 16 + col) * 32 + quad * 8);
#pragma unroll
    for (int j = 0; j < 4; ++j)
      bfr[j] = *(const bf16x8*)(Bsm + (wn + j * 16 + col) * 32 + quad * 8);
#pragma unroll
    for (int i = 0; i < 4; ++i)
#pragma unroll
      for (int j = 0; j < 4; ++j)
        acc[i][j] = __builtin_amdgcn_mfma_f32_16x16x32_bf16(af[i], bfr[j], acc[i][j], 0, 0, 0);
  }

  const float QS = 0.125f * 1.44269504088896f;
#pragma unroll
  for (int j = 0; j < 4; ++j) {
    const int n = bn * 128 + wn + j * 16 + col;
    const float bias = bqkv[n];
    const int region = n >> 10;
    const int hh = (n >> 6) & 15;
    const int dh = n & 63;
    if (region == 2) {
      const size_t baseT = ((size_t)(hb + hh) * 64 + dh) * 2048;
#pragma unroll
      for (int i = 0; i < 4; ++i) {
        const int srow = s0 + wm + i * 16 + quad * 4;
#pragma unroll
        for (int r = 0; r < 4; ++r)
          v[baseT + srow + r] = f2b(acc[i][j][r] + bias);
      }
    } else {
      u16* outp = (region == 0) ? q : kk;
      const float mult = (region == 0) ? QS : 1.0f;
      const size_t base = ((size_t)(hb + hh) * 2048) * 64 + dh;
#pragma unroll
      for (int i = 0; i < 4; ++i) {
        const int srow = s0 + wm + i * 16 + quad * 4;
#pragma unroll
        for (int r = 0; r < 4; ++r)
          outp[base + (size_t)(srow + r) * 64] = f2b((acc[i][j][r] + bias) * mult);
      }
    }
  }
}

// ---------------- K2: flash attention (merged 64-key softmax, spill-free) ----------------
// R8 regression root cause: ka[4][2]+sc[4] pushed live VGPRs past the
// launch_bounds(256,4) cap of 128 -> loop spills (WRITE_SIZE 16->38MB).
// Fix: mt-outer QK loop: only one ka pair (8 VGPRs) live at a time; scores
// for BOTH qt computed per mt into sc[2][4]. Peak live ~105 VGPRs.
__global__ __launch_bounds__(256, 4) void k_attn(
    const u16* __restrict__ q, const u16* __restrict__ k,
    const u16* __restrict__ v, const int* __restrict__ mask,
    u16* __restrict__ attn, int b_fixed) {
  __shared__ __align__(16) float Msmf[2048];  // 8KB mask bias row
  __shared__ __align__(16) u16 Ksm[64 * 64];  // 8KB
  __shared__ __align__(16) u16 Vsm[64 * 64];  // 8KB
  __shared__ __align__(16) u32 PsmU[4096];    // 16KB P relay (wave-private)
  const int bid = blockIdx.x;
  const int tid = threadIdx.x, wave = tid >> 6, lane = tid & 63;
  const int col = lane & 15, quad = lane >> 4;
  int qblk, h, b, hb;
  if (b_fixed < 0) { qblk = bid & 15; h = (bid >> 4) & 15; b = bid >> 8; hb = b * 16 + h; }
  else             { qblk = bid & 15; h = bid >> 4;        b = b_fixed;  hb = h; }
  const size_t bh = (size_t)hb * 2048 * 64;

  {  // stage mask row b (2048 int32)
    const int c = wave * 2;
    gld16(mask + b * 2048 + c * 256 + lane * 4, (char*)Msmf + c * 1024);
    gld16(mask + b * 2048 + (c + 1) * 256 + lane * 4, (char*)Msmf + (c + 1) * 1024);
  }
  __builtin_amdgcn_s_waitcnt(0);
  __syncthreads();
  for (int i = tid; i < 2048; i += 256) {
    const int mi = ((const int*)Msmf)[i];
    Msmf[i] = mi ? -1e30f : 0.f;
  }

  bf16x8 qf[2][2];
#pragma unroll
  for (int qt = 0; qt < 2; ++qt)
#pragma unroll
    for (int c = 0; c < 2; ++c)
      qf[qt][c] = *(const bf16x8*)(q + bh +
                   (size_t)(qblk * 128 + wave * 32 + qt * 16 + col) * 64 + c * 32 + quad * 8);

  f32x4 o[2][4];
#pragma unroll
  for (int qt = 0; qt < 2; ++qt)
#pragma unroll
    for (int n = 0; n < 4; ++n) o[qt][n] = f32x4{0.f, 0.f, 0.f, 0.f};
  float mrun[2] = {-1e30f, -1e30f}, lrun[2] = {0.f, 0.f};

  const int r8 = lane >> 3, chn = lane & 7;
  const int g = chn ^ r8;
  const int swz = col & 7;
  __syncthreads();

  for (int kt = 0; kt < 32; ++kt) {
    __syncthreads();
#pragma unroll
    for (int s = 0; s < 2; ++s) {
      const int row = (wave * 2 + s) * 8 + r8;
      gld16(k + bh + (size_t)(kt * 64 + row) * 64 + g * 8,
            (char*)Ksm + (wave * 2 + s) * 1024);
      gld16(v + bh + (size_t)row * 2048 + kt * 64 + g * 8,
            (char*)Vsm + (wave * 2 + s) * 1024);
    }
    __builtin_amdgcn_s_waitcnt(0);
    __syncthreads();

    // QK phase: mt-outer, one ka pair live; scores for both qt per mt.
    f32x4 sc[2][4];  // [qt][mt]
#pragma unroll
    for (int mt = 0; mt < 4; ++mt) {
      const bf16x8 ka0 = *(const bf16x8*)((const char*)Ksm +
          (mt * 16 + col) * 128 + (quad ^ swz) * 16);
      const bf16x8 ka1 = *(const bf16x8*)((const char*)Ksm +
          (mt * 16 + col) * 128 + ((4 + quad) ^ swz) * 16);
      const float4 mbv = *(const float4*)(Msmf + kt * 64 + mt * 16 + quad * 4);
#pragma unroll
      for (int qt = 0; qt < 2; ++qt) {
        f32x4 z = {mbv.x, mbv.y, mbv.z, mbv.w};  // mask bias as C-init
        z = __builtin_amdgcn_mfma_f32_16x16x32_bf16(ka0, qf[qt][0], z, 0, 0, 0);
        sc[qt][mt] = __builtin_amdgcn_mfma_f32_16x16x32_bf16(ka1, qf[qt][1], z, 0, 0, 0);
      }
    }

    float alpha[2];
#pragma unroll
    for (int qt = 0; qt < 2; ++qt) {
      float tm = fmaxf(fmaxf(sc[qt][0][0], sc[qt][0][1]),
                       fmaxf(sc[qt][0][2], sc[qt][0][3]));
#pragma unroll
      for (int mt = 1; mt < 4; ++mt)
#pragma unroll
        for (int r = 0; r < 4; ++r) tm = fmaxf(tm, sc[qt][mt][r]);
      tm = fmaxf(tm, __shfl_xor(tm, 16, 64));
      tm = fmaxf(tm, __shfl_xor(tm, 32, 64));
      const float mnew = fmaxf(mrun[qt], tm);
      alpha[qt] = __builtin_amdgcn_exp2f(mrun[qt] - mnew);
      mrun[qt] = mnew;
      float sum = 0.f;
#pragma unroll
      for (int mt = 0; mt < 4; ++mt)
#pragma unroll
        for (int r = 0; r < 4; ++r) {
          sc[qt][mt][r] = __builtin_amdgcn_exp2f(sc[qt][mt][r] - mnew);
          sum += sc[qt][mt][r];
        }
      sum += __shfl_xor(sum, 16, 64);
      sum += __shfl_xor(sum, 32, 64);
      lrun[qt] = lrun[qt] * alpha[qt] + sum;
      u32* pw = PsmU + (wave * 2 + qt) * 512 + quad * 32 + col * 2;
#pragma unroll
      for (int mt = 0; mt < 4; ++mt) {
        uint2 w;
        w.x = pk2(sc[qt][mt][0], sc[qt][mt][1]);
        w.y = pk2(sc[qt][mt][2], sc[qt][mt][3]);
        *(uint2*)(pw + mt * 128) = w;
      }
    }

    asm volatile("s_waitcnt lgkmcnt(0)" ::: "memory");

    bf16x8 pa[2][2];
#pragma unroll
    for (int qt = 0; qt < 2; ++qt)
#pragma unroll
      for (int c = 0; c < 2; ++c) {
        const u32* pr = PsmU + (wave * 2 + qt) * 512 + c * 256 + quad * 64 + col * 2;
        const uint2 a0 = *(const uint2*)pr;
        const uint2 a1 = *(const uint2*)(pr + 32);
        u32x4 w = {a0.x, a0.y, a1.x, a1.y};
        pa[qt][c] = __builtin_bit_cast(bf16x8, w);
      }

    float ar[2][4];
#pragma unroll
    for (int qt = 0; qt < 2; ++qt)
#pragma unroll
      for (int r = 0; r < 4; ++r) ar[qt][r] = __shfl(alpha[qt], quad * 4 + r, 64);

#pragma unroll
    for (int n = 0; n < 4; ++n) {
      const bf16x8 vb0 = *(const bf16x8*)((const char*)Vsm +
          (n * 16 + col) * 128 + (quad ^ swz) * 16);
      const bf16x8 vb1 = *(const bf16x8*)((const char*)Vsm +
          (n * 16 + col) * 128 + ((4 + quad) ^ swz) * 16);
#pragma unroll
      for (int qt = 0; qt < 2; ++qt) {
        f32x4 t = o[qt][n];
#pragma unroll
        for (int r = 0; r < 4; ++r) t[r] *= ar[qt][r];
        t = __builtin_amdgcn_mfma_f32_16x16x32_bf16(pa[qt][0], vb0, t, 0, 0, 0);
        o[qt][n] = __builtin_amdgcn_mfma_f32_16x16x32_bf16(pa[qt][1], vb1, t, 0, 0, 0);
      }
    }
  }

  const int arow0 = (b_fixed < 0) ? b * 2048 : 0;
#pragma unroll
  for (int qt = 0; qt < 2; ++qt) {
    float inv[4];
#pragma unroll
    for (int r = 0; r < 4; ++r) {
      const float lr = __shfl(lrun[qt], quad * 4 + r, 64);
      inv[r] = 1.0f / lr;
    }
#pragma unroll
    for (int n = 0; n < 4; ++n)
#pragma unroll
      for (int r = 0; r < 4; ++r) {
        const int srow = qblk * 128 + wave * 32 + qt * 16 + quad * 4 + r;
        const size_t idx = ((size_t)(arow0 + srow)) * 1024 + h * 64 + n * 16 + col;
        attn[idx] = f2b(o[qt][n][r] * inv[r]);
      }
  }
}

// ---------------- K3a: output projection, all-bf16 staging ----------------
__global__ __launch_bounds__(256, 2) void k_proj_a(
    const u16* __restrict__ attn, const u16* __restrict__ wb,
    const float* __restrict__ bproj, float* __restrict__ out) {
  __shared__ __align__(16) u16 Asm[128 * 32];
  __shared__ __align__(16) u16 Bsm[128 * 32];
  const int bn = blockIdx.x;  // 0..7
  const int bm = blockIdx.y;  // 0..63
  const int tid = threadIdx.x;
  const int wave = tid >> 6, lane = tid & 63;
  const int col = lane & 15, quad = lane >> 4;
  const int b = bm >> 4;
  const int s0 = (bm & 15) * 128;
  const int c0 = wave * 2;
  const int srow0 = c0 * 16 + (lane >> 2);
  const int kc = (lane & 3) * 8;
  const u16* gA0 = attn + (size_t)(bm * 128 + srow0) * 1024 + kc;
  const u16* gA1 = attn + (size_t)(bm * 128 + srow0 + 16) * 1024 + kc;
  const u16* gB0 = wb + (size_t)(bn * 128 + srow0) * 1024 + kc;
  const u16* gB1 = wb + (size_t)(bn * 128 + srow0 + 16) * 1024 + kc;
  u16* lA0 = Asm + c0 * 512;
  u16* lA1 = Asm + c0 * 512 + 512;
  u16* lB0 = Bsm + c0 * 512;
  u16* lB1 = Bsm + c0 * 512 + 512;
  const int wm = (wave >> 1) * 64, wn = (wave & 1) * 64;

  f32x4 acc[4][4];
#pragma unroll
  for (int i = 0; i < 4; ++i)
#pragma unroll
    for (int j = 0; j < 4; ++j) acc[i][j] = f32x4{0.f, 0.f, 0.f, 0.f};

  for (int k0 = 0; k0 < 1024; k0 += 32) {
    __syncthreads();
    gld16(gA0 + k0, lA0);
    gld16(gA1 + k0, lA1);
    gld16(gB0 + k0, lB0);
    gld16(gB1 + k0, lB1);
    __builtin_amdgcn_s_waitcnt(0);
    __syncthreads();
    bf16x8 af[4], bfr[4];
#pragma unroll
    for (int i = 0; i < 4; ++i)
      af[i] = *(const bf16x8*)(Asm + (wm + i * 16 + col) * 32 + quad * 8);
#pragma unroll
    for (int j = 0; j < 4; ++j)
      bfr[j] = *(const bf16x8*)(Bsm + (wn + j * 16 + col) * 32 + quad * 8);
#pragma unroll
    for (int i = 0; i < 4; ++i)
#pragma unroll
      for (int j = 0; j < 4; ++j)
        acc[i][j] = __builtin_amdgcn_mfma_f32_16x16x32_bf16(af[i], bfr[j], acc[i][j], 0, 0, 0);
  }

#pragma unroll
  for (int j = 0; j < 4; ++j) {
    const int n = bn * 128 + wn + j * 16 + col;
    const float bias = bproj[n];
#pragma unroll
    for (int i = 0; i < 4; ++i) {
      const int srow = s0 + wm + i * 16 + quad * 4;
#pragma unroll
      for (int r = 0; r < 4; ++r)
        out[(size_t)((srow + r) * 4 + b) * 1024 + n] = acc[i][j][r] + bias;
    }
  }
}

// ---------------- K3b: output projection, inline-convert B (fallback) ----------------
__global__ __launch_bounds__(256, 2) void k_proj_f32(
    const u16* __restrict__ attn, const float* __restrict__ Wproj,
    const float* __restrict__ bproj, float* __restrict__ out, int b_fixed) {
  __shared__ __align__(16) u16 Asm[128 * 32];
  __shared__ __align__(16) u16 Bsm[128 * 32];
  const int bn = blockIdx.x;
  const int bm = blockIdx.y;
  const int tid = threadIdx.x;
  const int wave = tid >> 6, lane = tid & 63;
  const int col = lane & 15, quad = lane >> 4;
  int b, s0;
  if (b_fixed < 0) { b = bm >> 4; s0 = (bm & 15) * 128; }
  else             { b = b_fixed; s0 = bm * 128; }

  const int c0 = wave * 2;
  const int srow0 = c0 * 16 + (lane >> 2);
  const int kc = (lane & 3) * 8;
  const u16* gA0 = attn + (size_t)(bm * 128 + srow0) * 1024 + kc;
  const u16* gA1 = attn + (size_t)(bm * 128 + srow0 + 16) * 1024 + kc;
  u16* lA0 = Asm + c0 * 512;
  u16* lA1 = Asm + c0 * 512 + 512;
  const int brow = tid >> 1;
  const int kseg = (tid & 1) * 16;
  const float* gB = Wproj + (size_t)(bn * 128 + brow) * 1024 + kseg;
  u16* lB = Bsm + brow * 32 + kseg;
  const int wm = (wave >> 1) * 64, wn = (wave & 1) * 64;

  f32x4 acc[4][4];
#pragma unroll
  for (int i = 0; i < 4; ++i)
#pragma unroll
    for (int j = 0; j < 4; ++j) acc[i][j] = f32x4{0.f, 0.f, 0.f, 0.f};

  for (int k0 = 0; k0 < 1024; k0 += 32) {
    float4 bv[4];
#pragma unroll
    for (int u = 0; u < 4; ++u) bv[u] = *(const float4*)(gB + k0 + u * 4);
    __syncthreads();
    gld16(gA0 + k0, lA0);
    gld16(gA1 + k0, lA1);
    cvt16_store(bv, lB);
    __builtin_amdgcn_s_waitcnt(0);
    __syncthreads();
    bf16x8 af[4], bfr[4];
#pragma unroll
    for (int i = 0; i < 4; ++i)
      af[i] = *(const bf16x8*)(Asm + (wm + i * 16 + col) * 32 + quad * 8);
#pragma unroll
    for (int j = 0; j < 4; ++j)
      bfr[j] = *(const bf16x8*)(Bsm + (wn + j * 16 + col) * 32 + quad * 8);
#pragma unroll
    for (int i = 0; i < 4; ++i)
#pragma unroll
      for (int j = 0; j < 4; ++j)
        acc[i][j] = __builtin_amdgcn_mfma_f32_16x16x32_bf16(af[i], bfr[j], acc[i][j], 0, 0, 0);
  }

#pragma unroll
  for (int j = 0; j < 4; ++j) {
    const int n = bn * 128 + wn + j * 16 + col;
    const float bias = bproj[n];
#pragma unroll
    for (int i = 0; i < 4; ++i) {
      const int srow = s0 + wm + i * 16 + quad * 4;
#pragma unroll
      for (int r = 0; r < 4; ++r)
        out[(size_t)((srow + r) * 4 + b) * 1024 + n] = acc[i][j][r] + bias;
    }
  }
}

extern "C" void kernel_launch(void* const* d_in, const int* in_sizes, int n_in,
                              void* d_out, int out_size, void* d_ws, size_t ws_size,
                              hipStream_t stream) {
  const float* inp = (const float*)d_in[0];
  const int* mask = (const int*)d_in[1];
  const float* Wqkv = (const float*)d_in[2];
  const float* bqkv = (const float*)d_in[3];
  const float* Wproj = (const float*)d_in[4];
  const float* bproj = (const float*)d_in[5];
  float* out = (float*)d_out;

  const size_t FULLSZ = (size_t)BATCH * NHEAD * SEQ * DHEAD;  // 8388608 elems
  const size_t WQKV_E = (size_t)3 * DIM * DIM;                // 3145728
  const size_t WPROJ_E = (size_t)DIM * DIM;                   // 1048576
  const size_t pathA_bytes = (4 * FULLSZ + WQKV_E + WPROJ_E) * sizeof(u16);  // 75.5 MB

  if (ws_size >= pathA_bytes) {
    // Path A: convert-once + all-async-bf16 GEMMs.
    u16* q = (u16*)d_ws;
    u16* kk = q + FULLSZ;
    u16* v = kk + FULLSZ;
    u16* xb = v + FULLSZ;      // converted inp; later overwritten as attn buffer
    u16* attn = xb;            // alias — k_attn writes after k_qkv_a finished reading
    u16* wqkvb = xb + FULLSZ;
    u16* wprojb = wqkvb + WQKV_E;
    k_cvt<<<dim3(12288), 256, 0, stream>>>(inp, Wqkv, Wproj, xb, wqkvb, wprojb);
    k_qkv_a<<<dim3(24, 64), 256, 0, stream>>>(xb, wqkvb, bqkv, q, kk, v);
    k_attn<<<dim3(1024), 256, 0, stream>>>(q, kk, v, mask, attn, -1);
    k_proj_a<<<dim3(8, 64), 256, 0, stream>>>(attn, wprojb, bproj, out);
  } else if (ws_size >= 4 * FULLSZ * sizeof(u16)) {
    // Path B: proven R5 pipeline (inline f32 convert).
    u16* q = (u16*)d_ws;
    u16* kk = q + FULLSZ;
    u16* v = kk + FULLSZ;
    u16* attn = v + FULLSZ;
    k_qkv_f32<<<dim3(24, 64), 256, 0, stream>>>(inp, Wqkv, bqkv, q, kk, v, -1);
    k_attn<<<dim3(1024), 256, 0, stream>>>(q, kk, v, mask, attn, -1);
    k_proj_f32<<<dim3(8, 64), 256, 0, stream>>>(attn, Wproj, bproj, out, -1);
  } else {
    // Path C: per-batch pipeline, 16 MiB workspace.
    const size_t BSZ = (size_t)NHEAD * SEQ * DHEAD;
    u16* q = (u16*)d_ws;
    u16* kk = q + BSZ;
    u16* v = kk + BSZ;
    u16* attn = v + BSZ;
    for (int b = 0; b < BATCH; ++b) {
      k_qkv_f32<<<dim3(24, 16), 256, 0, stream>>>(inp, Wqkv, bqkv, q, kk, v, b);
      k_attn<<<dim3(256), 256, 0, stream>>>(q, kk, v, mask, attn, b);
      k_proj_f32<<<dim3(8, 16), 256, 0, stream>>>(attn, Wproj, bproj, out, b);
    }
  }
}